// Round 2
// baseline (5466.068 us; speedup 1.0000x reference)
//
#include <hip/hip_runtime.h>

#define NTOK 32768
#define NE   2048
#define EDIM 128
#define NQ   4

#define TOKT 64          // tokens per block
#define CODT 512         // codes per tile
#define DCH  8           // d-rows per staged chunk
#define NTILE (NE / CODT)        // 4
#define NCHPT (EDIM / DCH)       // 16 chunks per tile
#define NCH   (NTILE * NCHPT)    // 64 total chunks

// ---------------------------------------------------------------------------
// per-code squared norms (sequential over 128 dims, same as reference order)
// + zero the loss accumulator
// ---------------------------------------------------------------------------
__global__ __launch_bounds__(256) void cnorm_init_kernel(
    const float* __restrict__ cb, float* __restrict__ cnorm,
    float* __restrict__ loss_accum)
{
    const int code = blockIdx.x * 256 + threadIdx.x;   // 0 .. NQ*NE-1
    if (code == 0) *loss_accum = 0.0f;
    const float4* row = (const float4*)(cb + (size_t)code * EDIM);
    float s = 0.0f;
#pragma unroll
    for (int j = 0; j < EDIM / 4; ++j) {
        float4 v = row[j];
        s += v.x * v.x; s += v.y * v.y; s += v.z * v.z; s += v.w * v.w;
    }
    cnorm[code] = s;
}

// ---------------------------------------------------------------------------
// codebook transpose: cbT[l][d][c] = cb[l][c][d]; 64-code tile per block
// ---------------------------------------------------------------------------
__global__ __launch_bounds__(256) void transpose_cb_kernel(
    const float* __restrict__ cb, float* __restrict__ cbT)
{
    __shared__ __align__(16) float S[64][129];
    const int t  = threadIdx.x;
    const int l  = blockIdx.x >> 5;
    const int c0 = (blockIdx.x & 31) * 64;
    const float* src = cb + ((size_t)l * NE + c0) * EDIM;
#pragma unroll
    for (int k = 0; k < 8; ++k) {
        const int idx = k * 256 + t;     // float4 idx 0..2047
        const int cc  = idx >> 5;        // code 0..63
        const int dq  = idx & 31;        // dim group
        float4 v = *(const float4*)(src + (size_t)cc * EDIM + dq * 4);
        S[cc][dq * 4 + 0] = v.x; S[cc][dq * 4 + 1] = v.y;
        S[cc][dq * 4 + 2] = v.z; S[cc][dq * 4 + 3] = v.w;
    }
    __syncthreads();
    float* dst = cbT + (size_t)l * EDIM * NE;
#pragma unroll
    for (int k = 0; k < 8; ++k) {
        const int idx = k * 256 + t;     // output float4 idx
        const int d   = idx >> 4;        // 0..127
        const int cq  = idx & 15;
        float4 w;
        w.x = S[cq * 4 + 0][d]; w.y = S[cq * 4 + 1][d];
        w.z = S[cq * 4 + 2][d]; w.w = S[cq * 4 + 3][d];
        *(float4*)(dst + (size_t)d * NE + c0 + cq * 4) = w;
    }
}

// ---------------------------------------------------------------------------
// One VQ level. 8x16 micro-tile, double-buffered B chunks from cbT.
// grid = NTOK/TOKT = 512 blocks, 256 threads, 64 KB LDS.
// ---------------------------------------------------------------------------
__global__ __launch_bounds__(256, 2) void vq_level_kernel(
    const float* __restrict__ rin,     // residual in [NTOK][EDIM]
    const float* __restrict__ cb,      // codebook [NE][EDIM] (gather)
    const float* __restrict__ cbT,     // transposed codebook [EDIM][NE]
    const float* __restrict__ cnorm,   // [NE]
    float* __restrict__ rout,
    float* __restrict__ xq,
    float* __restrict__ idx_out,       // float indices, stride NQ
    float* __restrict__ loss_accum,
    int level, int first)
{
    __shared__ __align__(16) float A[EDIM][TOKT];       // 32 KB
    __shared__ __align__(16) float Bsh[2][DCH][CODT];   // 32 KB (dbuf)

    // overlays (phase-disjoint with B buffer usage):
    float* part   = &Bsh[1][0][0];            // [4][64], pre-loop only
    float* ovl    = &Bsh[0][0][0];            // post-loop region
    float* red_df = ovl;                      // [4][64]
    int*   red_if = (int*)(ovl + 256);        // [4][64]
    int*   idx_s  = (int*)(ovl + 512);        // [64]
    float* lsum   = ovl + 576;                // [256]

    const int t    = threadIdx.x;
    const int tok0 = blockIdx.x * TOKT;
    const int tx   = t & 7;
    const int ty   = t >> 3;                  // 0..31
    const int tx8  = tx * 8;
    const int ty16 = ty * 16;

    // ---- stage residual tile (transposed) + partial norms ----
    {
        const int tok = t & 63;
        const int dg  = t >> 6;               // 0..3, 32 dims each
        float s = 0.0f;
#pragma unroll
        for (int j = 0; j < 8; ++j) {
            const int d0 = dg * 32 + j * 4;
            float4 v = *(const float4*)(rin + (size_t)(tok0 + tok) * EDIM + d0);
            A[d0 + 0][tok] = v.x; A[d0 + 1][tok] = v.y;
            A[d0 + 2][tok] = v.z; A[d0 + 3][tok] = v.w;
            s += v.x * v.x; s += v.y * v.y; s += v.z * v.z; s += v.w * v.w;
        }
        part[dg * 64 + tok] = s;
    }
    __syncthreads();   // bar1

    // per-thread token norms, same association as before: ((p0+p1)+p2)+p3
    float rn[8];
#pragma unroll
    for (int i = 0; i < 8; ++i) {
        const int tok = tx8 + i;
        rn[i] = ((part[tok] + part[64 + tok]) + part[128 + tok]) + part[192 + tok];
    }

    // ---- stage chunk 0 into buf0 (tile 0, dc 0) ----
#pragma unroll
    for (int k = 0; k < 4; ++k) {
        const int f4 = k * 256 + t;
        float4 v = *(const float4*)(cbT + (size_t)(f4 >> 7) * NE + (f4 & 127) * 4);
        *(float4*)(&Bsh[0][0][0] + f4 * 4) = v;
    }
    __syncthreads();   // bar2 (part reads done before this; buf1 untouched yet)

    float best_d[8], acc[8][16];
    int   best_i[8];
#pragma unroll
    for (int i = 0; i < 8; ++i) { best_d[i] = 3.402823466e38f; best_i[i] = 0; }

    for (int c = 0; c < NCH; ++c) {
        const int buf = c & 1;

        // ---- prefetch next chunk into registers (issue-early) ----
        float4 pf[4];
        const int cnx = c + 1;
        if (cnx < NCH) {
            const int ctn = cnx >> 4;         // tile of next chunk
            const int dcn = cnx & 15;         // chunk-in-tile
            const float* gsrc = cbT + (size_t)(dcn * DCH) * NE + (size_t)ctn * CODT;
#pragma unroll
            for (int k = 0; k < 4; ++k) {
                const int f4 = k * 256 + t;
                pf[k] = *(const float4*)(gsrc + (size_t)(f4 >> 7) * NE + (f4 & 127) * 4);
            }
        }

        if ((c & 15) == 0) {
#pragma unroll
            for (int i = 0; i < 8; ++i)
#pragma unroll
                for (int j = 0; j < 16; ++j) acc[i][j] = 0.0f;
        }

        // ---- compute: 8 d-steps x 128 FMA, d strictly ascending ----
        const float* Bb = &Bsh[buf][0][0];
        const int dbase = (c & 15) * DCH;
#pragma unroll
        for (int d = 0; d < DCH; ++d) {
            const float* Arow = &A[dbase + d][0];
            float4 a0 = *(const float4*)(Arow + tx8);
            float4 a1 = *(const float4*)(Arow + tx8 + 4);
            const float* Brow = Bb + d * CODT + ty16;
            float4 b0 = *(const float4*)(Brow);
            float4 b1 = *(const float4*)(Brow + 4);
            float4 b2 = *(const float4*)(Brow + 8);
            float4 b3 = *(const float4*)(Brow + 12);
            const float a[8]  = {a0.x, a0.y, a0.z, a0.w, a1.x, a1.y, a1.z, a1.w};
            const float b[16] = {b0.x, b0.y, b0.z, b0.w, b1.x, b1.y, b1.z, b1.w,
                                 b2.x, b2.y, b2.z, b2.w, b3.x, b3.y, b3.z, b3.w};
#pragma unroll
            for (int i = 0; i < 8; ++i)
#pragma unroll
                for (int j = 0; j < 16; ++j)
                    acc[i][j] += a[i] * b[j];
        }

        // ---- write prefetched chunk to the other buffer (write-late) ----
        if (cnx < NCH) {
            float* dst = &Bsh[buf ^ 1][0][0];
#pragma unroll
            for (int k = 0; k < 4; ++k)
                *(float4*)(dst + (k * 256 + t) * 4) = pf[k];
        }

        // ---- argmin update at tile end (registers only) ----
        if ((c & 15) == 15) {
            const int ct  = c >> 4;
            const int cb0 = ct * CODT + ty16;
            float4 q0 = *(const float4*)(cnorm + cb0);
            float4 q1 = *(const float4*)(cnorm + cb0 + 4);
            float4 q2 = *(const float4*)(cnorm + cb0 + 8);
            float4 q3 = *(const float4*)(cnorm + cb0 + 12);
            const float cnv[16] = {q0.x, q0.y, q0.z, q0.w, q1.x, q1.y, q1.z, q1.w,
                                   q2.x, q2.y, q2.z, q2.w, q3.x, q3.y, q3.z, q3.w};
#pragma unroll
            for (int i = 0; i < 8; ++i) {
                const float rni = rn[i];
#pragma unroll
                for (int j = 0; j < 16; ++j) {
                    const float dist = (rni - 2.0f * acc[i][j]) + cnv[j];
                    if (dist < best_d[i]) {        // strict < : first occurrence
                        best_d[i] = dist;
                        best_i[i] = cb0 + j;
                    }
                }
            }
        }
        __syncthreads();
    }

    // ---- in-wave argmin reduce across ty' (lanes sharing tx) ----
#pragma unroll
    for (int m = 8; m < 64; m <<= 1) {
#pragma unroll
        for (int i = 0; i < 8; ++i) {
            float od = __shfl_xor(best_d[i], m, 64);
            int   oi = __shfl_xor(best_i[i], m, 64);
            if (od < best_d[i] || (od == best_d[i] && oi < best_i[i])) {
                best_d[i] = od; best_i[i] = oi;
            }
        }
    }
    if ((t & 63) < 8) {                       // one lane per tx per wave
        const int w = t >> 6;
#pragma unroll
        for (int i = 0; i < 8; ++i) {
            red_df[w * 64 + tx8 + i] = best_d[i];
            red_if[w * 64 + tx8 + i] = best_i[i];
        }
    }
    __syncthreads();
    if (t < 64) {
        float bd = red_df[t];
        int   bi = red_if[t];
#pragma unroll
        for (int w = 1; w < 4; ++w) {
            const float dd = red_df[w * 64 + t];
            const int   ii = red_if[w * 64 + t];
            if (dd < bd || (dd == bd && ii < bi)) { bd = dd; bi = ii; }
        }
        idx_s[t] = bi;
        idx_out[(size_t)(tok0 + t) * NQ + level] = (float)bi;
    }
    __syncthreads();

    // ---- epilogue: gather + straight-through update + loss partial ----
    {
        const int tok = t >> 2;      // 0..63
        const int dq  = t & 3;       // 4 threads per token
        const int gi  = idx_s[tok];
        const float* qrow = cb + (size_t)gi * EDIM;
        float lp = 0.0f;
#pragma unroll
        for (int k = 0; k < 8; ++k) {
            const int d0 = k * 16 + dq * 4;
            const float4 q = *(const float4*)(qrow + d0);
            float4 r;
            r.x = A[d0 + 0][tok]; r.y = A[d0 + 1][tok];
            r.z = A[d0 + 2][tok]; r.w = A[d0 + 3][tok];
            float4 tq, qst, rnv;
            tq.x = q.x - r.x; tq.y = q.y - r.y; tq.z = q.z - r.z; tq.w = q.w - r.w;
            qst.x = r.x + tq.x; qst.y = r.y + tq.y;
            qst.z = r.z + tq.z; qst.w = r.w + tq.w;
            rnv.x = r.x - qst.x; rnv.y = r.y - qst.y;
            rnv.z = r.z - qst.z; rnv.w = r.w - qst.w;
            const size_t go = (size_t)(tok0 + tok) * EDIM + d0;
            *(float4*)(rout + go) = rnv;
            if (first) {
                *(float4*)(xq + go) = qst;
            } else {
                float4 o = *(const float4*)(xq + go);
                o.x += qst.x; o.y += qst.y; o.z += qst.z; o.w += qst.w;
                *(float4*)(xq + go) = o;
            }
            lp += tq.x * tq.x; lp += tq.y * tq.y;
            lp += tq.z * tq.z; lp += tq.w * tq.w;
        }
        lsum[t] = lp;
    }
    __syncthreads();
#pragma unroll
    for (int s2 = 128; s2 > 0; s2 >>= 1) {
        if (t < s2) lsum[t] += lsum[t + s2];
        __syncthreads();
    }
    if (t == 0) atomicAdd(loss_accum, lsum[0]);
}

// ---------------------------------------------------------------------------
__global__ void finalize_kernel(const float* __restrict__ loss_accum,
                                float* __restrict__ out_loss)
{
    *out_loss = *loss_accum * (1.25f / (4.0f * (float)NTOK * (float)EDIM));
}

extern "C" void kernel_launch(void* const* d_in, const int* in_sizes, int n_in,
                              void* d_out, int out_size, void* d_ws, size_t ws_size,
                              hipStream_t stream)
{
    const float* x  = (const float*)d_in[0];   // [NTOK][EDIM]
    const float* cb = (const float*)d_in[1];   // [NQ][NE][EDIM]

    float* out      = (float*)d_out;
    float* xq       = out;
    float* out_loss = out + (size_t)NTOK * EDIM;
    float* idx_out  = out + (size_t)NTOK * EDIM + 1;

    float* ws         = (float*)d_ws;
    float* cnorm      = ws;                        // NQ*NE floats
    float* loss_accum = ws + 8192;
    float* cbT        = ws + 8448;                 // NQ*EDIM*NE floats (4M)
    float* r0         = cbT + (size_t)NQ * EDIM * NE;  // NTOK*EDIM floats

    transpose_cb_kernel<<<NQ * (NE / 64), 256, 0, stream>>>(cb, cbT);
    cnorm_init_kernel<<<(NQ * NE) / 256, 256, 0, stream>>>(cb, cnorm, loss_accum);

    for (int l = 0; l < NQ; ++l) {
        const float* rin = (l == 0) ? x : r0;    // in-place for l>=1 (rows disjoint per block)
        vq_level_kernel<<<NTOK / TOKT, 256, 0, stream>>>(
            rin,
            cb + (size_t)l * NE * EDIM,
            cbT + (size_t)l * EDIM * NE,
            cnorm + (size_t)l * NE,
            r0, xq, idx_out, loss_accum, l, (l == 0) ? 1 : 0);
    }
    finalize_kernel<<<1, 1, 0, stream>>>(loss_accum, out_loss);
}

// Round 3
// 2818.850 us; speedup vs baseline: 1.9391x; 1.9391x over previous
//
#include <hip/hip_runtime.h>

#define NTOK 32768
#define NE   2048
#define EDIM 128
#define NQ   4

#define TOKT 64          // tokens per block
#define CODT 512         // codes per tile
#define DCH  8           // d-rows per staged chunk
#define NTILE (NE / CODT)        // 4
#define NCHPT (EDIM / DCH)       // 16 chunks per tile
#define NCH   (NTILE * NCHPT)    // 64 total chunks

// ---------------------------------------------------------------------------
__global__ __launch_bounds__(256) void cnorm_init_kernel(
    const float* __restrict__ cb, float* __restrict__ cnorm,
    float* __restrict__ loss_accum)
{
    const int code = blockIdx.x * 256 + threadIdx.x;   // 0 .. NQ*NE-1
    if (code == 0) *loss_accum = 0.0f;
    const float4* row = (const float4*)(cb + (size_t)code * EDIM);
    float s = 0.0f;
#pragma unroll
    for (int j = 0; j < EDIM / 4; ++j) {
        float4 v = row[j];
        s += v.x * v.x; s += v.y * v.y; s += v.z * v.z; s += v.w * v.w;
    }
    cnorm[code] = s;
}

// ---------------------------------------------------------------------------
// codebook transpose: cbT[l][d][c] = cb[l][c][d]
// ---------------------------------------------------------------------------
__global__ __launch_bounds__(256) void transpose_cb_kernel(
    const float* __restrict__ cb, float* __restrict__ cbT)
{
    __shared__ __align__(16) float S[64][129];
    const int t  = threadIdx.x;
    const int l  = blockIdx.x >> 5;
    const int c0 = (blockIdx.x & 31) * 64;
    const float* src = cb + ((size_t)l * NE + c0) * EDIM;
#pragma unroll
    for (int k = 0; k < 8; ++k) {
        const int idx = k * 256 + t;
        const int cc  = idx >> 5;
        const int dq  = idx & 31;
        float4 v = *(const float4*)(src + (size_t)cc * EDIM + dq * 4);
        S[cc][dq * 4 + 0] = v.x; S[cc][dq * 4 + 1] = v.y;
        S[cc][dq * 4 + 2] = v.z; S[cc][dq * 4 + 3] = v.w;
    }
    __syncthreads();
    float* dst = cbT + (size_t)l * EDIM * NE;
#pragma unroll
    for (int k = 0; k < 8; ++k) {
        const int idx = k * 256 + t;
        const int d   = idx >> 4;
        const int cq  = idx & 15;
        float4 w;
        w.x = S[cq * 4 + 0][d]; w.y = S[cq * 4 + 1][d];
        w.z = S[cq * 4 + 2][d]; w.w = S[cq * 4 + 3][d];
        *(float4*)(dst + (size_t)d * NE + c0 + cq * 4) = w;
    }
}

// ---------------------------------------------------------------------------
// register-tile macros: NO stack aggregates anywhere in the hot kernel
// ---------------------------------------------------------------------------
#define F4FMA(C, S, B) { C.x += (S)*(B).x; C.y += (S)*(B).y; \
                         C.z += (S)*(B).z; C.w += (S)*(B).w; }

#define DECL_ROW(i) float4 acc##i##_0, acc##i##_1, acc##i##_2, acc##i##_3;
#define ZERO_ROW(i) { acc##i##_0 = z4; acc##i##_1 = z4; \
                      acc##i##_2 = z4; acc##i##_3 = z4; }
#define FMA_ROW(i, S) { F4FMA(acc##i##_0, S, b0) F4FMA(acc##i##_1, S, b1) \
                        F4FMA(acc##i##_2, S, b2) F4FMA(acc##i##_3, S, b3) }

#define ACMP(i, AV, CV, J) { const float dd = (rni - 2.0f*(AV)) + (CV); \
    if (dd < bd##i) { bd##i = dd; bi##i = cb0 + (J); } }
#define ARGROW(i) { const float rni = rn##i; \
    ACMP(i, acc##i##_0.x, q0.x, 0)  ACMP(i, acc##i##_0.y, q0.y, 1) \
    ACMP(i, acc##i##_0.z, q0.z, 2)  ACMP(i, acc##i##_0.w, q0.w, 3) \
    ACMP(i, acc##i##_1.x, q1.x, 4)  ACMP(i, acc##i##_1.y, q1.y, 5) \
    ACMP(i, acc##i##_1.z, q1.z, 6)  ACMP(i, acc##i##_1.w, q1.w, 7) \
    ACMP(i, acc##i##_2.x, q2.x, 8)  ACMP(i, acc##i##_2.y, q2.y, 9) \
    ACMP(i, acc##i##_2.z, q2.z, 10) ACMP(i, acc##i##_2.w, q2.w, 11) \
    ACMP(i, acc##i##_3.x, q3.x, 12) ACMP(i, acc##i##_3.y, q3.y, 13) \
    ACMP(i, acc##i##_3.z, q3.z, 14) ACMP(i, acc##i##_3.w, q3.w, 15) }

#define RED(i) { float od = __shfl_xor(bd##i, m, 64); \
                 int   oi = __shfl_xor(bi##i, m, 64); \
    if (od < bd##i || (od == bd##i && oi < bi##i)) { bd##i = od; bi##i = oi; } }

#define STB(i) { red_df[w * 64 + tx8 + i] = bd##i; \
                 red_if[w * 64 + tx8 + i] = bi##i; }

#define RNI(i) const float rn##i = ((part[tx8 + i] + part[64 + tx8 + i]) \
                 + part[128 + tx8 + i]) + part[192 + tx8 + i];

__device__ __forceinline__ void gld16(const float* g, const float* l) {
    __builtin_amdgcn_global_load_lds(
        (const __attribute__((address_space(1))) unsigned int*)(const void*)g,
        (__attribute__((address_space(3))) unsigned int*)(void*)(uintptr_t)
            ((const void*)l) == nullptr ? nullptr :
        (__attribute__((address_space(3))) unsigned int*)(void*)(l),
        16, 0, 0);
}

// ---------------------------------------------------------------------------
// One VQ level. 8x16 register micro-tile, dbuf B via global_load_lds,
// XOR-swizzled B layout (inverse-swizzled global source, swizzled read).
// grid = 512 blocks, 256 threads, 64 KB LDS.
// ---------------------------------------------------------------------------
__global__ __launch_bounds__(256, 2) void vq_level_kernel(
    const float* __restrict__ rin,
    const float* __restrict__ cb,      // row-major codebook (gather)
    const float* __restrict__ cbT,     // transposed codebook [EDIM][NE]
    const float* __restrict__ cnorm,
    float* __restrict__ rout,
    float* __restrict__ xq,
    float* __restrict__ idx_out,
    float* __restrict__ loss_accum,
    int level, int first)
{
    __shared__ __align__(16) float A[EDIM][TOKT];       // 32 KB
    __shared__ __align__(16) float Bsh[2][DCH][CODT];   // 32 KB (dbuf)

    float* part   = &Bsh[1][0][0];            // [4][64], pre-loop only
    float* ovl    = &Bsh[0][0][0];            // post-loop overlays
    float* red_df = ovl;                      // [4][64]
    int*   red_if = (int*)(ovl + 256);        // [4][64]
    int*   idx_s  = (int*)(ovl + 512);        // [64]
    float* lsum   = ovl + 576;                // [256]

    const int t    = threadIdx.x;
    const int tok0 = blockIdx.x * TOKT;
    const int tx   = t & 7;
    const int ty   = t >> 3;                  // 0..31
    const int tx8  = tx * 8;
    const int ty16 = ty * 16;
    const int xo   = ((ty >> 1) & 3) << 2;    // read-side swizzle (floats)
    const int tl   = t ^ ((t >> 3) & 3);      // inverse swizzle for staging
    const int grow0 = tl >> 7;                // 0/1
    const int gcol4 = (tl & 127) * 4;         // float col within tile
    const float* ldsw = &Bsh[0][0][0] + (t & 192) * 4;   // wave-uniform base

    // ---- stage residual tile (transposed) + partial norms ----
    {
        const int tok = t & 63;
        const int dg  = t >> 6;
        float s = 0.0f;
#pragma unroll
        for (int j = 0; j < 8; ++j) {
            const int d0 = dg * 32 + j * 4;
            float4 v = *(const float4*)(rin + (size_t)(tok0 + tok) * EDIM + d0);
            A[d0 + 0][tok] = v.x; A[d0 + 1][tok] = v.y;
            A[d0 + 2][tok] = v.z; A[d0 + 3][tok] = v.w;
            s += v.x * v.x; s += v.y * v.y; s += v.z * v.z; s += v.w * v.w;
        }
        part[dg * 64 + tok] = s;
    }
    __syncthreads();   // bar1

    RNI(0) RNI(1) RNI(2) RNI(3) RNI(4) RNI(5) RNI(6) RNI(7)

    // ---- stage chunk 0 into buf0 (tile 0, dc 0) via global_load_lds ----
    {
        const float* gsrc = cbT + (size_t)grow0 * NE + gcol4;
        const float* ld   = ldsw;                       // Bsh[0] wave base
        gld16(gsrc,          ld);
        gld16(gsrc + 2 * NE, ld + 1024);
        gld16(gsrc + 4 * NE, ld + 2048);
        gld16(gsrc + 6 * NE, ld + 3072);
    }
    __syncthreads();   // bar2: chunk0 resident (barrier drains vmcnt)

    float bd0, bd1, bd2, bd3, bd4, bd5, bd6, bd7;
    int   bi0, bi1, bi2, bi3, bi4, bi5, bi6, bi7;
    bd0 = bd1 = bd2 = bd3 = bd4 = bd5 = bd6 = bd7 = 3.402823466e38f;
    bi0 = bi1 = bi2 = bi3 = bi4 = bi5 = bi6 = bi7 = 0;

    DECL_ROW(0) DECL_ROW(1) DECL_ROW(2) DECL_ROW(3)
    DECL_ROW(4) DECL_ROW(5) DECL_ROW(6) DECL_ROW(7)
    const float4 z4 = make_float4(0.f, 0.f, 0.f, 0.f);

    for (int tile = 0; tile < NTILE; ++tile) {
        ZERO_ROW(0) ZERO_ROW(1) ZERO_ROW(2) ZERO_ROW(3)
        ZERO_ROW(4) ZERO_ROW(5) ZERO_ROW(6) ZERO_ROW(7)

        for (int dc = 0; dc < NCHPT; ++dc) {
            const int c   = tile * NCHPT + dc;
            const int buf = c & 1;

            // ---- issue next chunk's DMA into buf^1 ----
            const int cnx = c + 1;
            if (cnx < NCH) {
                const int tile_n = cnx >> 4;
                const int dc_n   = cnx & 15;
                const float* gsrc = cbT + (size_t)(dc_n * DCH + grow0) * NE
                                    + tile_n * CODT + gcol4;
                const float* ld = ldsw + (buf ^ 1) * (DCH * CODT);
                gld16(gsrc,          ld);
                gld16(gsrc + 2 * NE, ld + 1024);
                gld16(gsrc + 4 * NE, ld + 2048);
                gld16(gsrc + 6 * NE, ld + 3072);
            }

            // ---- compute 8 d-steps from buf ----
            const float* Bb   = &Bsh[buf][0][0];
            const int dbase   = dc * DCH;
#pragma unroll
            for (int d = 0; d < DCH; ++d) {
                const float* Arow = &A[dbase + d][tx8];
                float4 a0 = *(const float4*)(Arow);
                float4 a1 = *(const float4*)(Arow + 4);
                const float* Brow = Bb + d * CODT + ty16;
                float4 b0 = *(const float4*)(Brow + xo);
                float4 b1 = *(const float4*)(Brow + (xo ^ 4));
                float4 b2 = *(const float4*)(Brow + (xo ^ 8));
                float4 b3 = *(const float4*)(Brow + (xo ^ 12));
                FMA_ROW(0, a0.x) FMA_ROW(1, a0.y)
                FMA_ROW(2, a0.z) FMA_ROW(3, a0.w)
                FMA_ROW(4, a1.x) FMA_ROW(5, a1.y)
                FMA_ROW(6, a1.z) FMA_ROW(7, a1.w)
            }
            __syncthreads();   // buf^1 DMA drained; buf free for overwrite
        }

        // ---- argmin over this tile's 16 columns (registers only) ----
        {
            const int cb0 = tile * CODT + ty16;
            const float4 q0 = *(const float4*)(cnorm + cb0);
            const float4 q1 = *(const float4*)(cnorm + cb0 + 4);
            const float4 q2 = *(const float4*)(cnorm + cb0 + 8);
            const float4 q3 = *(const float4*)(cnorm + cb0 + 12);
            ARGROW(0) ARGROW(1) ARGROW(2) ARGROW(3)
            ARGROW(4) ARGROW(5) ARGROW(6) ARGROW(7)
        }
    }

    // ---- in-wave argmin reduce across ty (lanes sharing tx) ----
    for (int m = 8; m < 64; m <<= 1) {
        RED(0) RED(1) RED(2) RED(3) RED(4) RED(5) RED(6) RED(7)
    }
    if ((t & 63) < 8) {
        const int w = t >> 6;
        STB(0) STB(1) STB(2) STB(3) STB(4) STB(5) STB(6) STB(7)
    }
    __syncthreads();
    if (t < 64) {
        float bdv = red_df[t];
        int   biv = red_if[t];
#pragma unroll
        for (int w = 1; w < 4; ++w) {
            const float dd = red_df[w * 64 + t];
            const int   ii = red_if[w * 64 + t];
            if (dd < bdv || (dd == bdv && ii < biv)) { bdv = dd; biv = ii; }
        }
        idx_s[t] = biv;
        idx_out[(size_t)(tok0 + t) * NQ + level] = (float)biv;
    }
    __syncthreads();

    // ---- epilogue: gather + straight-through update + loss partial ----
    {
        const int tok = t >> 2;
        const int dq  = t & 3;
        const int gi  = idx_s[tok];
        const float* qrow = cb + (size_t)gi * EDIM;
        float lp = 0.0f;
#pragma unroll
        for (int k = 0; k < 8; ++k) {
            const int d0 = k * 16 + dq * 4;
            const float4 q = *(const float4*)(qrow + d0);
            float4 r;
            r.x = A[d0 + 0][tok]; r.y = A[d0 + 1][tok];
            r.z = A[d0 + 2][tok]; r.w = A[d0 + 3][tok];
            float4 tq, qst, rnv;
            tq.x = q.x - r.x; tq.y = q.y - r.y; tq.z = q.z - r.z; tq.w = q.w - r.w;
            qst.x = r.x + tq.x; qst.y = r.y + tq.y;
            qst.z = r.z + tq.z; qst.w = r.w + tq.w;
            rnv.x = r.x - qst.x; rnv.y = r.y - qst.y;
            rnv.z = r.z - qst.z; rnv.w = r.w - qst.w;
            const size_t go = (size_t)(tok0 + tok) * EDIM + d0;
            *(float4*)(rout + go) = rnv;
            if (first) {
                *(float4*)(xq + go) = qst;
            } else {
                float4 o = *(const float4*)(xq + go);
                o.x += qst.x; o.y += qst.y; o.z += qst.z; o.w += qst.w;
                *(float4*)(xq + go) = o;
            }
            lp += tq.x * tq.x; lp += tq.y * tq.y;
            lp += tq.z * tq.z; lp += tq.w * tq.w;
        }
        lsum[t] = lp;
    }
    __syncthreads();
#pragma unroll
    for (int s2 = 128; s2 > 0; s2 >>= 1) {
        if (t < s2) lsum[t] += lsum[t + s2];
        __syncthreads();
    }
    if (t == 0) atomicAdd(loss_accum, lsum[0]);
}

// ---------------------------------------------------------------------------
__global__ void finalize_kernel(const float* __restrict__ loss_accum,
                                float* __restrict__ out_loss)
{
    *out_loss = *loss_accum * (1.25f / (4.0f * (float)NTOK * (float)EDIM));
}

extern "C" void kernel_launch(void* const* d_in, const int* in_sizes, int n_in,
                              void* d_out, int out_size, void* d_ws, size_t ws_size,
                              hipStream_t stream)
{
    const float* x  = (const float*)d_in[0];
    const float* cb = (const float*)d_in[1];

    float* out      = (float*)d_out;
    float* xq       = out;
    float* out_loss = out + (size_t)NTOK * EDIM;
    float* idx_out  = out + (size_t)NTOK * EDIM + 1;

    float* ws         = (float*)d_ws;
    float* cnorm      = ws;
    float* loss_accum = ws + 8192;
    float* cbT        = ws + 8448;
    float* r0         = cbT + (size_t)NQ * EDIM * NE;

    transpose_cb_kernel<<<NQ * (NE / 64), 256, 0, stream>>>(cb, cbT);
    cnorm_init_kernel<<<(NQ * NE) / 256, 256, 0, stream>>>(cb, cnorm, loss_accum);

    for (int l = 0; l < NQ; ++l) {
        const float* rin = (l == 0) ? x : r0;
        vq_level_kernel<<<NTOK / TOKT, 256, 0, stream>>>(
            rin,
            cb + (size_t)l * NE * EDIM,
            cbT + (size_t)l * EDIM * NE,
            cnorm + (size_t)l * NE,
            r0, xq, idx_out, loss_accum, l, (l == 0) ? 1 : 0);
    }
    finalize_kernel<<<1, 1, 0, stream>>>(loss_accum, out_loss);
}

// Round 4
// 1416.609 us; speedup vs baseline: 3.8586x; 1.9899x over previous
//
#include <hip/hip_runtime.h>

#define NTOK 32768
#define NE   2048
#define EDIM 128
#define NQ   4

#define TOKT 64          // tokens per block
#define CODT 512         // codes per tile
#define DCH  8           // d-rows per staged chunk
#define NTILE (NE / CODT)        // 4
#define NCHPT (EDIM / DCH)       // 16 chunks per tile
#define NCH   (NTILE * NCHPT)    // 64 total chunks

// ---------------------------------------------------------------------------
__global__ __launch_bounds__(256) void cnorm_init_kernel(
    const float* __restrict__ cb, float* __restrict__ cnorm,
    float* __restrict__ loss_accum)
{
    const int code = blockIdx.x * 256 + threadIdx.x;   // 0 .. NQ*NE-1
    if (code == 0) *loss_accum = 0.0f;
    const float4* row = (const float4*)(cb + (size_t)code * EDIM);
    float s = 0.0f;
#pragma unroll
    for (int j = 0; j < EDIM / 4; ++j) {
        float4 v = row[j];
        s += v.x * v.x; s += v.y * v.y; s += v.z * v.z; s += v.w * v.w;
    }
    cnorm[code] = s;
}

// ---------------------------------------------------------------------------
// codebook transpose: cbT[l][d][c] = cb[l][c][d]
// ---------------------------------------------------------------------------
__global__ __launch_bounds__(256) void transpose_cb_kernel(
    const float* __restrict__ cb, float* __restrict__ cbT)
{
    __shared__ __align__(16) float S[64][129];
    const int t  = threadIdx.x;
    const int l  = blockIdx.x >> 5;
    const int c0 = (blockIdx.x & 31) * 64;
    const float* src = cb + ((size_t)l * NE + c0) * EDIM;
#pragma unroll
    for (int k = 0; k < 8; ++k) {
        const int idx = k * 256 + t;
        const int cc  = idx >> 5;
        const int dq  = idx & 31;
        float4 v = *(const float4*)(src + (size_t)cc * EDIM + dq * 4);
        S[cc][dq * 4 + 0] = v.x; S[cc][dq * 4 + 1] = v.y;
        S[cc][dq * 4 + 2] = v.z; S[cc][dq * 4 + 3] = v.w;
    }
    __syncthreads();
    float* dst = cbT + (size_t)l * EDIM * NE;
#pragma unroll
    for (int k = 0; k < 8; ++k) {
        const int idx = k * 256 + t;
        const int d   = idx >> 4;
        const int cq  = idx & 15;
        float4 w;
        w.x = S[cq * 4 + 0][d]; w.y = S[cq * 4 + 1][d];
        w.z = S[cq * 4 + 2][d]; w.w = S[cq * 4 + 3][d];
        *(float4*)(dst + (size_t)d * NE + c0 + cq * 4) = w;
    }
}

// ---------------------------------------------------------------------------
// register-tile macros: NO stack aggregates anywhere in the hot kernel
// ---------------------------------------------------------------------------
#define F4FMA(C, S, B) { C.x += (S)*(B).x; C.y += (S)*(B).y; \
                         C.z += (S)*(B).z; C.w += (S)*(B).w; }

#define DECL_ROW(i) float4 acc##i##_0, acc##i##_1, acc##i##_2, acc##i##_3;
#define ZERO_ROW(i) { acc##i##_0 = z4; acc##i##_1 = z4; \
                      acc##i##_2 = z4; acc##i##_3 = z4; }
#define FMA_ROW(i, S) { F4FMA(acc##i##_0, S, b0) F4FMA(acc##i##_1, S, b1) \
                        F4FMA(acc##i##_2, S, b2) F4FMA(acc##i##_3, S, b3) }

#define ACMP(i, AV, CV, J) { const float dd = (rni - 2.0f*(AV)) + (CV); \
    if (dd < bd##i) { bd##i = dd; bi##i = cb0 + (J); } }
#define ARGROW(i) { const float rni = rn##i; \
    ACMP(i, acc##i##_0.x, q0.x, 0)  ACMP(i, acc##i##_0.y, q0.y, 1) \
    ACMP(i, acc##i##_0.z, q0.z, 2)  ACMP(i, acc##i##_0.w, q0.w, 3) \
    ACMP(i, acc##i##_1.x, q1.x, 4)  ACMP(i, acc##i##_1.y, q1.y, 5) \
    ACMP(i, acc##i##_1.z, q1.z, 6)  ACMP(i, acc##i##_1.w, q1.w, 7) \
    ACMP(i, acc##i##_2.x, q2.x, 8)  ACMP(i, acc##i##_2.y, q2.y, 9) \
    ACMP(i, acc##i##_2.z, q2.z, 10) ACMP(i, acc##i##_2.w, q2.w, 11) \
    ACMP(i, acc##i##_3.x, q3.x, 12) ACMP(i, acc##i##_3.y, q3.y, 13) \
    ACMP(i, acc##i##_3.z, q3.z, 14) ACMP(i, acc##i##_3.w, q3.w, 15) }

#define RED(i) { float od = __shfl_xor(bd##i, m, 64); \
                 int   oi = __shfl_xor(bi##i, m, 64); \
    if (od < bd##i || (od == bd##i && oi < bi##i)) { bd##i = od; bi##i = oi; } }

#define STB(i) { red_df[w * 64 + tx8 + i] = bd##i; \
                 red_if[w * 64 + tx8 + i] = bi##i; }

#define RNI(i) const float rn##i = ((part[tx8 + i] + part[64 + tx8 + i]) \
                 + part[128 + tx8 + i]) + part[192 + tx8 + i];

__device__ __forceinline__ void gld16(const float* g, const float* l) {
    __builtin_amdgcn_global_load_lds(
        (const __attribute__((address_space(1))) unsigned int*)(const void*)g,
        (__attribute__((address_space(3))) unsigned int*)(void*)(uintptr_t)
            ((const void*)l) == nullptr ? nullptr :
        (__attribute__((address_space(3))) unsigned int*)(void*)(l),
        16, 0, 0);
}

// ---------------------------------------------------------------------------
// One VQ level. 8x16 register micro-tile, dbuf B via global_load_lds,
// XOR-swizzled B layout (inverse-swizzled global source, swizzled read).
// grid = 512 blocks, 256 threads, 64 KB LDS, 2 blocks/CU (LDS-bound).
// amdgpu_waves_per_eu(1): lift the VGPR cap to 512 — round 3's (256,2)
// capped the allocator at 128 VGPRs and spilled ~60 regs -> 2.35 GB of
// scratch HBM traffic. Demand is ~190; occupancy stays 2/SIMD (LDS-bound).
// ---------------------------------------------------------------------------
__attribute__((amdgpu_waves_per_eu(1)))
__global__ __launch_bounds__(256) void vq_level_kernel(
    const float* __restrict__ rin,
    const float* __restrict__ cb,      // row-major codebook (gather)
    const float* __restrict__ cbT,     // transposed codebook [EDIM][NE]
    const float* __restrict__ cnorm,
    float* __restrict__ rout,
    float* __restrict__ xq,
    float* __restrict__ idx_out,
    float* __restrict__ loss_accum,
    int level, int first)
{
    __shared__ __align__(16) float A[EDIM][TOKT];       // 32 KB
    __shared__ __align__(16) float Bsh[2][DCH][CODT];   // 32 KB (dbuf)

    float* part   = &Bsh[1][0][0];            // [4][64], pre-loop only
    float* ovl    = &Bsh[0][0][0];            // post-loop overlays
    float* red_df = ovl;                      // [4][64]
    int*   red_if = (int*)(ovl + 256);        // [4][64]
    int*   idx_s  = (int*)(ovl + 512);        // [64]
    float* lsum   = ovl + 576;                // [256]

    const int t    = threadIdx.x;
    const int tok0 = blockIdx.x * TOKT;
    const int tx   = t & 7;
    const int ty   = t >> 3;                  // 0..31
    const int tx8  = tx * 8;
    const int ty16 = ty * 16;
    const int xo   = ((ty >> 1) & 3) << 2;    // read-side swizzle (floats)
    const int tl   = t ^ ((t >> 3) & 3);      // inverse swizzle for staging
    const int grow0 = tl >> 7;                // 0/1
    const int gcol4 = (tl & 127) * 4;         // float col within tile
    const float* ldsw = &Bsh[0][0][0] + (t & 192) * 4;   // wave-uniform base

    // ---- stage residual tile (transposed) + partial norms ----
    {
        const int tok = t & 63;
        const int dg  = t >> 6;
        float s = 0.0f;
#pragma unroll
        for (int j = 0; j < 8; ++j) {
            const int d0 = dg * 32 + j * 4;
            float4 v = *(const float4*)(rin + (size_t)(tok0 + tok) * EDIM + d0);
            A[d0 + 0][tok] = v.x; A[d0 + 1][tok] = v.y;
            A[d0 + 2][tok] = v.z; A[d0 + 3][tok] = v.w;
            s += v.x * v.x; s += v.y * v.y; s += v.z * v.z; s += v.w * v.w;
        }
        part[dg * 64 + tok] = s;
    }
    __syncthreads();   // bar1

    RNI(0) RNI(1) RNI(2) RNI(3) RNI(4) RNI(5) RNI(6) RNI(7)

    // ---- stage chunk 0 into buf0 (tile 0, dc 0) via global_load_lds ----
    {
        const float* gsrc = cbT + (size_t)grow0 * NE + gcol4;
        const float* ld   = ldsw;                       // Bsh[0] wave base
        gld16(gsrc,          ld);
        gld16(gsrc + 2 * NE, ld + 1024);
        gld16(gsrc + 4 * NE, ld + 2048);
        gld16(gsrc + 6 * NE, ld + 3072);
    }
    __syncthreads();   // bar2: chunk0 resident (barrier drains vmcnt)

    float bd0, bd1, bd2, bd3, bd4, bd5, bd6, bd7;
    int   bi0, bi1, bi2, bi3, bi4, bi5, bi6, bi7;
    bd0 = bd1 = bd2 = bd3 = bd4 = bd5 = bd6 = bd7 = 3.402823466e38f;
    bi0 = bi1 = bi2 = bi3 = bi4 = bi5 = bi6 = bi7 = 0;

    DECL_ROW(0) DECL_ROW(1) DECL_ROW(2) DECL_ROW(3)
    DECL_ROW(4) DECL_ROW(5) DECL_ROW(6) DECL_ROW(7)
    const float4 z4 = make_float4(0.f, 0.f, 0.f, 0.f);

    for (int tile = 0; tile < NTILE; ++tile) {
        ZERO_ROW(0) ZERO_ROW(1) ZERO_ROW(2) ZERO_ROW(3)
        ZERO_ROW(4) ZERO_ROW(5) ZERO_ROW(6) ZERO_ROW(7)

        for (int dc = 0; dc < NCHPT; ++dc) {
            const int c   = tile * NCHPT + dc;
            const int buf = c & 1;

            // ---- issue next chunk's DMA into buf^1 ----
            const int cnx = c + 1;
            if (cnx < NCH) {
                const int tile_n = cnx >> 4;
                const int dc_n   = cnx & 15;
                const float* gsrc = cbT + (size_t)(dc_n * DCH + grow0) * NE
                                    + tile_n * CODT + gcol4;
                const float* ld = ldsw + (buf ^ 1) * (DCH * CODT);
                gld16(gsrc,          ld);
                gld16(gsrc + 2 * NE, ld + 1024);
                gld16(gsrc + 4 * NE, ld + 2048);
                gld16(gsrc + 6 * NE, ld + 3072);
            }

            // ---- compute 8 d-steps from buf ----
            const float* Bb   = &Bsh[buf][0][0];
            const int dbase   = dc * DCH;
#pragma unroll
            for (int d = 0; d < DCH; ++d) {
                const float* Arow = &A[dbase + d][tx8];
                float4 a0 = *(const float4*)(Arow);
                float4 a1 = *(const float4*)(Arow + 4);
                const float* Brow = Bb + d * CODT + ty16;
                float4 b0 = *(const float4*)(Brow + xo);
                float4 b1 = *(const float4*)(Brow + (xo ^ 4));
                float4 b2 = *(const float4*)(Brow + (xo ^ 8));
                float4 b3 = *(const float4*)(Brow + (xo ^ 12));
                FMA_ROW(0, a0.x) FMA_ROW(1, a0.y)
                FMA_ROW(2, a0.z) FMA_ROW(3, a0.w)
                FMA_ROW(4, a1.x) FMA_ROW(5, a1.y)
                FMA_ROW(6, a1.z) FMA_ROW(7, a1.w)
            }
            __syncthreads();   // buf^1 DMA drained; buf free for overwrite
        }

        // ---- argmin over this tile's 16 columns (registers only) ----
        {
            const int cb0 = tile * CODT + ty16;
            const float4 q0 = *(const float4*)(cnorm + cb0);
            const float4 q1 = *(const float4*)(cnorm + cb0 + 4);
            const float4 q2 = *(const float4*)(cnorm + cb0 + 8);
            const float4 q3 = *(const float4*)(cnorm + cb0 + 12);
            ARGROW(0) ARGROW(1) ARGROW(2) ARGROW(3)
            ARGROW(4) ARGROW(5) ARGROW(6) ARGROW(7)
        }
    }

    // ---- in-wave argmin reduce across ty (lanes sharing tx) ----
    for (int m = 8; m < 64; m <<= 1) {
        RED(0) RED(1) RED(2) RED(3) RED(4) RED(5) RED(6) RED(7)
    }
    if ((t & 63) < 8) {
        const int w = t >> 6;
        STB(0) STB(1) STB(2) STB(3) STB(4) STB(5) STB(6) STB(7)
    }
    __syncthreads();
    if (t < 64) {
        float bdv = red_df[t];
        int   biv = red_if[t];
#pragma unroll
        for (int w = 1; w < 4; ++w) {
            const float dd = red_df[w * 64 + t];
            const int   ii = red_if[w * 64 + t];
            if (dd < bdv || (dd == bdv && ii < biv)) { bdv = dd; biv = ii; }
        }
        idx_s[t] = biv;
        idx_out[(size_t)(tok0 + t) * NQ + level] = (float)biv;
    }
    __syncthreads();

    // ---- epilogue: gather + straight-through update + loss partial ----
    {
        const int tok = t >> 2;
        const int dq  = t & 3;
        const int gi  = idx_s[tok];
        const float* qrow = cb + (size_t)gi * EDIM;
        float lp = 0.0f;
#pragma unroll
        for (int k = 0; k < 8; ++k) {
            const int d0 = k * 16 + dq * 4;
            const float4 q = *(const float4*)(qrow + d0);
            float4 r;
            r.x = A[d0 + 0][tok]; r.y = A[d0 + 1][tok];
            r.z = A[d0 + 2][tok]; r.w = A[d0 + 3][tok];
            float4 tq, qst, rnv;
            tq.x = q.x - r.x; tq.y = q.y - r.y; tq.z = q.z - r.z; tq.w = q.w - r.w;
            qst.x = r.x + tq.x; qst.y = r.y + tq.y;
            qst.z = r.z + tq.z; qst.w = r.w + tq.w;
            rnv.x = r.x - qst.x; rnv.y = r.y - qst.y;
            rnv.z = r.z - qst.z; rnv.w = r.w - qst.w;
            const size_t go = (size_t)(tok0 + tok) * EDIM + d0;
            *(float4*)(rout + go) = rnv;
            if (first) {
                *(float4*)(xq + go) = qst;
            } else {
                float4 o = *(const float4*)(xq + go);
                o.x += qst.x; o.y += qst.y; o.z += qst.z; o.w += qst.w;
                *(float4*)(xq + go) = o;
            }
            lp += tq.x * tq.x; lp += tq.y * tq.y;
            lp += tq.z * tq.z; lp += tq.w * tq.w;
        }
        lsum[t] = lp;
    }
    __syncthreads();
#pragma unroll
    for (int s2 = 128; s2 > 0; s2 >>= 1) {
        if (t < s2) lsum[t] += lsum[t + s2];
        __syncthreads();
    }
    if (t == 0) atomicAdd(loss_accum, lsum[0]);
}

// ---------------------------------------------------------------------------
__global__ void finalize_kernel(const float* __restrict__ loss_accum,
                                float* __restrict__ out_loss)
{
    *out_loss = *loss_accum * (1.25f / (4.0f * (float)NTOK * (float)EDIM));
}

extern "C" void kernel_launch(void* const* d_in, const int* in_sizes, int n_in,
                              void* d_out, int out_size, void* d_ws, size_t ws_size,
                              hipStream_t stream)
{
    const float* x  = (const float*)d_in[0];
    const float* cb = (const float*)d_in[1];

    float* out      = (float*)d_out;
    float* xq       = out;
    float* out_loss = out + (size_t)NTOK * EDIM;
    float* idx_out  = out + (size_t)NTOK * EDIM + 1;

    float* ws         = (float*)d_ws;
    float* cnorm      = ws;
    float* loss_accum = ws + 8192;
    float* cbT        = ws + 8448;
    float* r0         = cbT + (size_t)NQ * EDIM * NE;

    transpose_cb_kernel<<<NQ * (NE / 64), 256, 0, stream>>>(cb, cbT);
    cnorm_init_kernel<<<(NQ * NE) / 256, 256, 0, stream>>>(cb, cnorm, loss_accum);

    for (int l = 0; l < NQ; ++l) {
        const float* rin = (l == 0) ? x : r0;
        vq_level_kernel<<<NTOK / TOKT, 256, 0, stream>>>(
            rin,
            cb + (size_t)l * NE * EDIM,
            cbT + (size_t)l * EDIM * NE,
            cnorm + (size_t)l * NE,
            r0, xq, idx_out, loss_accum, l, (l == 0) ? 1 : 0);
    }
    finalize_kernel<<<1, 1, 0, stream>>>(loss_accum, out_loss);
}